// Round 6
// baseline (131.083 us; speedup 1.0000x reference)
//
#include <hip/hip_runtime.h>
#include <math.h>

#define NB 4096
#define NN 10000
#define PADN 10240            // keys padded to TILE multiple with +inf sentinels
#define ND 256
#define ALPHA 0.2f
#define CS 16                 // rows per chunk / items per rank block
#define NG (NN / CS)          // 625 chunks (exact)
#define NPB (NB / CS)         // 256 patient rank blocks (exact)
#define SCHUNK 25             // chunks per superchunk
#define NSUPER (NG / SCHUNK)  // 25 superchunks (exact)
#define RSEGS 32              // rank segments per block (16 slots x 32 segs = 512 thr)
#define TILE 2048             // keys staged in LDS per pass
#define NTILES (PADN / TILE)  // 5 (exact)
#define TSEG (TILE / RSEGS)   // 64 keys per thread per tile (exact)
#define ZELEMS (2 * NSUPER * ND + 2 * NSUPER)  // SSA + SSC + ssa0 + ssc0

typedef unsigned long long u64;

__device__ __forceinline__ unsigned mono32(float x) {
  unsigned bits = __float_as_uint(x);
  return bits ^ (((int)bits >> 31) | 0x80000000u);  // order-preserving map
}

// --- 1) dot scores t_n=V[n]·Wn, s_b=P[b]·Wp (one wave per row); sortable
// u64 keys tk[n] (strict total order: float-monotone uint32 <<14 | index);
// sentinel-pad tk[NN..PADN); zero the atomic accumulator region.
__global__ __launch_bounds__(256) void k_dot(
    const float* __restrict__ P, const float* __restrict__ V,
    const float* __restrict__ K,
    float* __restrict__ t, float* __restrict__ s, u64* __restrict__ tk,
    int* __restrict__ zero_region) {
  int gt = blockIdx.x * 256 + threadIdx.x;
  if (gt < ZELEMS) zero_region[gt] = 0;
  if (gt < PADN - NN) tk[NN + gt] = ~0ull;   // sentinels: never < any real key
  int j = blockIdx.x * 4 + (threadIdx.x >> 6);
  int lane = threadIdx.x & 63;
  if (j >= NN + NB) return;
  const float* row; const float* wv; int oi; bool isn;
  if (j < NN) { row = V + (size_t)j * ND; wv = K + ND; oi = j; isn = true; }
  else        { row = P + (size_t)(j - NN) * ND; wv = K; oi = j - NN; isn = false; }
  float4 r  = ((const float4*)row)[lane];
  float4 kx = ((const float4*)wv)[lane];
  float acc = r.x * kx.x + r.y * kx.y + r.z * kx.z + r.w * kx.w;
  #pragma unroll
  for (int off = 32; off; off >>= 1) acc += __shfl_down(acc, off, 64);
  if (lane == 0) {
    if (isn) {
      t[oi] = acc;
      tk[oi] = ((u64)mono32(acc) << 14) | (unsigned)oi;
    } else {
      s[oi] = acc;
    }
  }
}

// --- 2) fused rank + scatter + patient-threshold rank, LDS-tiled, 512-thr.
// Blocks 0..624: node rows [16g,16g+16) -> exact rank -> scatter.
// Blocks 625..880: patients [16(g-625),+16): kk[b] = #{m: t_m < -s_b}
//   (θ==0 canonicalized to -0.0 preserving strict-< lower_bound semantics).
// 512 threads = 16 slots x 32 segments; 5 tiles of 2048 keys in LDS
// (sentinel-padded); per-slot broadcast reads are conflict-free.
// 8 waves/block -> ~6.9 waves/SIMD at grid 881: hides ds_read latency.
__global__ __launch_bounds__(512) void k_ranksc(
    const u64* __restrict__ tk, const float* __restrict__ t,
    const float* __restrict__ s,
    float* __restrict__ eA, float* __restrict__ eC,
    int* __restrict__ idxs, int* __restrict__ kk) {
  __shared__ u64 kt[TILE];
  __shared__ int lr[CS][RSEGS + 1];
  int g = blockIdx.x;                 // 0..880
  int nl = threadIdx.x & 15;          // slot
  int seg = threadIdx.x >> 4;         // key segment within tile (0..31)
  bool isn = (g < NG);
  u64 kn;
  if (isn) {
    kn = tk[g * CS + nl];
  } else {
    float th = -s[(g - NG) * CS + nl];
    if (th == 0.0f) th = -0.0f;       // exclude t==-0 when θ==+0 (strict <)
    kn = (u64)mono32(th) << 14;
  }
  int r0 = 0, r1 = 0;
  for (int tile = 0; tile < NTILES; ++tile) {
    #pragma unroll
    for (int m = threadIdx.x; m < TILE; m += 512)
      kt[m] = tk[tile * TILE + m];
    __syncthreads();
    int m0 = seg * TSEG;
    #pragma unroll 8
    for (int m = m0; m < m0 + TSEG; m += 2) {   // 2 independent add chains
      r0 += (kt[m] < kn);
      r1 += (kt[m + 1] < kn);
    }
    __syncthreads();
  }
  lr[nl][seg] = r0 + r1;
  __syncthreads();
  if (threadIdx.x < CS) {
    int rr = 0;
    #pragma unroll
    for (int q = 0; q < RSEGS; ++q) rr += lr[threadIdx.x][q];
    if (isn) {
      int n2 = g * CS + threadIdx.x;
      float tn = t[n2];
      eA[rr] = __expf(tn);
      eC[rr] = __expf(ALPHA * tn);
      idxs[rr] = n2;
    } else {
      kk[(g - NG) * CS + threadIdx.x] = rr;
    }
  }
}

// --- 3) per-chunk sums (rank order) + atomic superchunk sums.
__global__ __launch_bounds__(256) void k_chunk(
    const float* __restrict__ eA, const float* __restrict__ eC,
    const int* __restrict__ idxs, const float* __restrict__ V,
    float* __restrict__ SA, float* __restrict__ SC,
    float* __restrict__ sa0, float* __restrict__ sc0,
    float* __restrict__ SSA, float* __restrict__ SSC,
    float* __restrict__ ssa0, float* __restrict__ ssc0) {
  int g = blockIdx.x, d = threadIdx.x;
  int base = g * CS;
  float accA = 0.f, accC = 0.f, sa = 0.f, sc = 0.f;
  #pragma unroll
  for (int j = 0; j < CS; ++j) {
    int i = base + j;
    float ea = eA[i], ec = eC[i];
    float v = V[(size_t)idxs[i] * ND + d];
    accA += ea * v; accC += ec * v;
    sa += ea; sc += ec;
  }
  SA[(size_t)g * ND + d] = accA;
  SC[(size_t)g * ND + d] = accC;
  int gs = g / SCHUNK;
  atomicAdd(&SSA[(size_t)gs * ND + d], accA);
  atomicAdd(&SSC[(size_t)gs * ND + d], accC);
  if (d == 0) {
    sa0[g] = sa; sc0[g] = sc;
    atomicAdd(&ssa0[gs], sa);
    atomicAdd(&ssc0[gs], sc);
  }
}

// --- 4) finalize: A-side as suffix sums, C-side as prefix sums (25 SS rows
// + <=24 chunk rows + <=15 V rows per block), fused epilogue.
__global__ __launch_bounds__(256) void k_finalize(
    const float* __restrict__ P, const float* __restrict__ V,
    const float* __restrict__ s, const int* __restrict__ kk,
    const float* __restrict__ eA, const float* __restrict__ eC,
    const int* __restrict__ idxs,
    const float* __restrict__ SA, const float* __restrict__ SC,
    const float* __restrict__ sa0, const float* __restrict__ sc0,
    const float* __restrict__ SSA, const float* __restrict__ SSC,
    const float* __restrict__ ssa0, const float* __restrict__ ssc0,
    float* __restrict__ out) {
  int b = blockIdx.x, d = threadIdx.x;
  int k = kk[b];
  int g = k >> 4;          // chunk idx; k==NN -> g==NG
  int gs = g / SCHUNK;     // superchunk idx; g==NG -> gs==NSUPER
  float suffA = 0.f, prefC = 0.f, suffa = 0.f, prefc = 0.f;
  for (int q = gs; q < NSUPER; ++q) {
    suffA += SSA[(size_t)q * ND + d];
    suffa += ssa0[q];
  }
  for (int q = 0; q < gs; ++q) {
    prefC += SSC[(size_t)q * ND + d];
    prefc += ssc0[q];
  }
  for (int j = gs * SCHUNK; j < g; ++j) {
    suffA -= SA[(size_t)j * ND + d];
    prefC += SC[(size_t)j * ND + d];
    suffa -= sa0[j];
    prefc += sc0[j];
  }
  for (int i = g << 4; i < k; ++i) {
    float ea = eA[i], ec = eC[i];
    float v = V[(size_t)idxs[i] * ND + d];
    suffA -= ea * v; prefC += ec * v;
    suffa -= ea;     prefc += ec;
  }
  float sb = s[b];
  float ea = __expf(sb), ec = __expf(ALPHA * sb);
  float l = ea * suffa + ec * prefc;
  float agg = (ea * suffA + ec * prefC) / l;
  out[(size_t)b * ND + d] = P[(size_t)b * ND + d] + agg;
}

extern "C" void kernel_launch(void* const* d_in, const int* in_sizes, int n_in,
                              void* d_out, int out_size, void* d_ws, size_t ws_size,
                              hipStream_t stream) {
  const float* P = (const float*)d_in[0];   // (B, D)
  const float* V = (const float*)d_in[1];   // (N, D)
  const float* K = (const float*)d_in[2];   // (2D, 1)
  float* out = (float*)d_out;

  char* w = (char*)d_ws;
  u64*   tk    = (u64*)w;   w += sizeof(u64) * PADN;      // 8B-aligned first
  // --- zeroed-by-k_dot region (contiguous): SSA, SSC, ssa0, ssc0 ---
  int*   zreg  = (int*)w;
  float* SSA   = (float*)w; w += sizeof(float) * NSUPER * ND;
  float* SSC   = (float*)w; w += sizeof(float) * NSUPER * ND;
  float* ssa0  = (float*)w; w += sizeof(float) * NSUPER;
  float* ssc0  = (float*)w; w += sizeof(float) * NSUPER;
  // --- rest ---
  float* t     = (float*)w; w += sizeof(float) * NN;
  float* s     = (float*)w; w += sizeof(float) * NB;
  float* eA    = (float*)w; w += sizeof(float) * NN;
  float* eC    = (float*)w; w += sizeof(float) * NN;
  int*   idxs  = (int*)w;   w += sizeof(int) * NN;
  int*   kk    = (int*)w;   w += sizeof(int) * NB;
  float* SA    = (float*)w; w += sizeof(float) * (size_t)NG * ND;
  float* SC    = (float*)w; w += sizeof(float) * (size_t)NG * ND;
  float* sa0   = (float*)w; w += sizeof(float) * NG;
  float* sc0   = (float*)w; w += sizeof(float) * NG;

  k_dot<<<(NN + NB + 3) / 4, 256, 0, stream>>>(P, V, K, t, s, tk, zreg);
  k_ranksc<<<NG + NPB, 512, 0, stream>>>(tk, t, s, eA, eC, idxs, kk);
  k_chunk<<<NG, 256, 0, stream>>>(eA, eC, idxs, V,
                                  SA, SC, sa0, sc0,
                                  SSA, SSC, ssa0, ssc0);
  k_finalize<<<NB, 256, 0, stream>>>(P, V, s, kk, eA, eC, idxs,
                                     SA, SC, sa0, sc0, SSA, SSC, ssa0, ssc0, out);
}

// Round 7
// 126.936 us; speedup vs baseline: 1.0327x; 1.0327x over previous
//
#include <hip/hip_runtime.h>
#include <math.h>

#define NB 4096
#define NN 10000
#define ND 256
#define ALPHA 0.2f
#define CS 16                 // rows per chunk / items per rank block
#define NG (NN / CS)          // 625 chunks (exact)
#define NPB (NB / CS)         // 256 patient rank blocks (exact)
#define SCHUNK 25             // chunks per superchunk
#define NSUPER (NG / SCHUNK)  // 25 superchunks (exact)
#define RSEGS 16              // rank segments per block (16 slots x 16 segs)
#define TILE 2000             // keys staged in LDS per pass
#define NTILES (NN / TILE)    // 5 (exact)
#define TSEG (TILE / RSEGS)   // 125 keys per thread per tile (exact)
#define ZELEMS (2 * NSUPER * ND + 2 * NSUPER)  // SSA + SSC + ssa0 + ssc0

typedef unsigned long long u64;

__device__ __forceinline__ unsigned mono32(float x) {
  unsigned bits = __float_as_uint(x);
  return bits ^ (((int)bits >> 31) | 0x80000000u);  // order-preserving map
}

// --- 1) dot scores t_n=V[n]·Wn, s_b=P[b]·Wp (one wave per row); sortable
// u64 keys tk[n] (strict total order: float-monotone uint32 <<14 | index);
// zero the atomic accumulator region (SSA/SSC/ssa0/ssc0).
__global__ __launch_bounds__(256) void k_dot(
    const float* __restrict__ P, const float* __restrict__ V,
    const float* __restrict__ K,
    float* __restrict__ t, float* __restrict__ s, u64* __restrict__ tk,
    int* __restrict__ zero_region) {
  int gt = blockIdx.x * 256 + threadIdx.x;
  if (gt < ZELEMS) zero_region[gt] = 0;
  int j = blockIdx.x * 4 + (threadIdx.x >> 6);
  int lane = threadIdx.x & 63;
  if (j >= NN + NB) return;
  const float* row; const float* wv; int oi; bool isn;
  if (j < NN) { row = V + (size_t)j * ND; wv = K + ND; oi = j; isn = true; }
  else        { row = P + (size_t)(j - NN) * ND; wv = K; oi = j - NN; isn = false; }
  float4 r  = ((const float4*)row)[lane];
  float4 kx = ((const float4*)wv)[lane];
  float acc = r.x * kx.x + r.y * kx.y + r.z * kx.z + r.w * kx.w;
  #pragma unroll
  for (int off = 32; off; off >>= 1) acc += __shfl_down(acc, off, 64);
  if (lane == 0) {
    if (isn) {
      t[oi] = acc;
      tk[oi] = ((u64)mono32(acc) << 14) | (unsigned)oi;
    } else {
      s[oi] = acc;
    }
  }
}

// --- 2) fused rank + scatter + patient-threshold rank, LDS-tiled.
// Blocks 0..624: node rows [16g,16g+16) -> exact rank -> scatter
//   tsort-free: eA/eC/idxs written at rank position.
// Blocks 625..880: patients [16(g-625),+16): kk[b] = #{m: t_m < -s_b}
//   (θ==0 canonicalized to -0.0 preserving strict-< lower_bound semantics).
// 256 threads = 16 slots x 16 segments; 5 tiles of 2000 keys in LDS;
// per-slot broadcast reads are bank-conflict-free.
__global__ __launch_bounds__(256) void k_ranksc(
    const u64* __restrict__ tk, const float* __restrict__ t,
    const float* __restrict__ s,
    float* __restrict__ eA, float* __restrict__ eC,
    int* __restrict__ idxs, int* __restrict__ kk) {
  __shared__ u64 kt[TILE];
  __shared__ int lr[CS][RSEGS + 1];
  int g = blockIdx.x;                 // 0..880
  int nl = threadIdx.x & 15;          // slot
  int seg = threadIdx.x >> 4;         // key segment within tile
  bool isn = (g < NG);
  u64 kn;
  if (isn) {
    kn = tk[g * CS + nl];
  } else {
    float th = -s[(g - NG) * CS + nl];
    if (th == 0.0f) th = -0.0f;       // exclude t==-0 when θ==+0 (strict <)
    kn = (u64)mono32(th) << 14;
  }
  int r = 0;
  for (int tile = 0; tile < NTILES; ++tile) {
    for (int m = threadIdx.x; m < TILE; m += 256)
      kt[m] = tk[tile * TILE + m];
    __syncthreads();
    int m0 = seg * TSEG;
    #pragma unroll 5
    for (int m = m0; m < m0 + TSEG; ++m) r += (kt[m] < kn);
    __syncthreads();
  }
  lr[nl][seg] = r;
  __syncthreads();
  if (threadIdx.x < CS) {
    int rr = 0;
    #pragma unroll
    for (int q = 0; q < RSEGS; ++q) rr += lr[threadIdx.x][q];
    if (isn) {
      int n2 = g * CS + threadIdx.x;
      float tn = t[n2];
      eA[rr] = __expf(tn);
      eC[rr] = __expf(ALPHA * tn);
      idxs[rr] = n2;
    } else {
      kk[(g - NG) * CS + threadIdx.x] = rr;
    }
  }
}

// --- 3) per-chunk sums (rank order) + atomic superchunk sums.
__global__ __launch_bounds__(256) void k_chunk(
    const float* __restrict__ eA, const float* __restrict__ eC,
    const int* __restrict__ idxs, const float* __restrict__ V,
    float* __restrict__ SA, float* __restrict__ SC,
    float* __restrict__ sa0, float* __restrict__ sc0,
    float* __restrict__ SSA, float* __restrict__ SSC,
    float* __restrict__ ssa0, float* __restrict__ ssc0) {
  int g = blockIdx.x, d = threadIdx.x;
  int base = g * CS;
  float accA = 0.f, accC = 0.f, sa = 0.f, sc = 0.f;
  #pragma unroll
  for (int j = 0; j < CS; ++j) {
    int i = base + j;
    float ea = eA[i], ec = eC[i];
    float v = V[(size_t)idxs[i] * ND + d];
    accA += ea * v; accC += ec * v;
    sa += ea; sc += ec;
  }
  SA[(size_t)g * ND + d] = accA;
  SC[(size_t)g * ND + d] = accC;
  int gs = g / SCHUNK;
  atomicAdd(&SSA[(size_t)gs * ND + d], accA);
  atomicAdd(&SSC[(size_t)gs * ND + d], accC);
  if (d == 0) {
    sa0[g] = sa; sc0[g] = sc;
    atomicAdd(&ssa0[gs], sa);
    atomicAdd(&ssc0[gs], sc);
  }
}

// --- 4) finalize: A-side as suffix sums, C-side as prefix sums (25 SS rows
// + <=24 chunk rows + <=15 V rows per block), fused epilogue.
__global__ __launch_bounds__(256) void k_finalize(
    const float* __restrict__ P, const float* __restrict__ V,
    const float* __restrict__ s, const int* __restrict__ kk,
    const float* __restrict__ eA, const float* __restrict__ eC,
    const int* __restrict__ idxs,
    const float* __restrict__ SA, const float* __restrict__ SC,
    const float* __restrict__ sa0, const float* __restrict__ sc0,
    const float* __restrict__ SSA, const float* __restrict__ SSC,
    const float* __restrict__ ssa0, const float* __restrict__ ssc0,
    float* __restrict__ out) {
  int b = blockIdx.x, d = threadIdx.x;
  int k = kk[b];
  int g = k >> 4;          // chunk idx; k==NN -> g==NG
  int gs = g / SCHUNK;     // superchunk idx; g==NG -> gs==NSUPER
  float suffA = 0.f, prefC = 0.f, suffa = 0.f, prefc = 0.f;
  for (int q = gs; q < NSUPER; ++q) {
    suffA += SSA[(size_t)q * ND + d];
    suffa += ssa0[q];
  }
  for (int q = 0; q < gs; ++q) {
    prefC += SSC[(size_t)q * ND + d];
    prefc += ssc0[q];
  }
  for (int j = gs * SCHUNK; j < g; ++j) {
    suffA -= SA[(size_t)j * ND + d];
    prefC += SC[(size_t)j * ND + d];
    suffa -= sa0[j];
    prefc += sc0[j];
  }
  for (int i = g << 4; i < k; ++i) {
    float ea = eA[i], ec = eC[i];
    float v = V[(size_t)idxs[i] * ND + d];
    suffA -= ea * v; prefC += ec * v;
    suffa -= ea;     prefc += ec;
  }
  float sb = s[b];
  float ea = __expf(sb), ec = __expf(ALPHA * sb);
  float l = ea * suffa + ec * prefc;
  float agg = (ea * suffA + ec * prefC) / l;
  out[(size_t)b * ND + d] = P[(size_t)b * ND + d] + agg;
}

extern "C" void kernel_launch(void* const* d_in, const int* in_sizes, int n_in,
                              void* d_out, int out_size, void* d_ws, size_t ws_size,
                              hipStream_t stream) {
  const float* P = (const float*)d_in[0];   // (B, D)
  const float* V = (const float*)d_in[1];   // (N, D)
  const float* K = (const float*)d_in[2];   // (2D, 1)
  float* out = (float*)d_out;

  char* w = (char*)d_ws;
  u64*   tk    = (u64*)w;   w += sizeof(u64) * NN;        // 8B-aligned first
  // --- zeroed-by-k_dot region (contiguous): SSA, SSC, ssa0, ssc0 ---
  int*   zreg  = (int*)w;
  float* SSA   = (float*)w; w += sizeof(float) * NSUPER * ND;
  float* SSC   = (float*)w; w += sizeof(float) * NSUPER * ND;
  float* ssa0  = (float*)w; w += sizeof(float) * NSUPER;
  float* ssc0  = (float*)w; w += sizeof(float) * NSUPER;
  // --- rest ---
  float* t     = (float*)w; w += sizeof(float) * NN;
  float* s     = (float*)w; w += sizeof(float) * NB;
  float* eA    = (float*)w; w += sizeof(float) * NN;
  float* eC    = (float*)w; w += sizeof(float) * NN;
  int*   idxs  = (int*)w;   w += sizeof(int) * NN;
  int*   kk    = (int*)w;   w += sizeof(int) * NB;
  float* SA    = (float*)w; w += sizeof(float) * (size_t)NG * ND;
  float* SC    = (float*)w; w += sizeof(float) * (size_t)NG * ND;
  float* sa0   = (float*)w; w += sizeof(float) * NG;
  float* sc0   = (float*)w; w += sizeof(float) * NG;

  k_dot<<<(NN + NB + 3) / 4, 256, 0, stream>>>(P, V, K, t, s, tk, zreg);
  k_ranksc<<<NG + NPB, 256, 0, stream>>>(tk, t, s, eA, eC, idxs, kk);
  k_chunk<<<NG, 256, 0, stream>>>(eA, eC, idxs, V,
                                  SA, SC, sa0, sc0,
                                  SSA, SSC, ssa0, ssc0);
  k_finalize<<<NB, 256, 0, stream>>>(P, V, s, kk, eA, eC, idxs,
                                     SA, SC, sa0, sc0, SSA, SSC, ssa0, ssc0, out);
}